// Round 3
// baseline (95.917 us; speedup 1.0000x reference)
//
#include <hip/hip_runtime.h>

#define NB 65536
#define NN 128
#define FDIM 16
#define ODIM 64
#define NBLK 512

typedef __attribute__((ext_vector_type(8))) short s16x8;
typedef __attribute__((ext_vector_type(4))) float f32x4;
typedef __attribute__((address_space(3))) void lds_void_t;
typedef const __attribute__((address_space(1))) void gbl_void_t;

__device__ __forceinline__ unsigned short f2bf_rne(float f) {
    unsigned u = __builtin_bit_cast(unsigned, f);
    u += 0x7FFFu + ((u >> 16) & 1u);
    return (unsigned short)(u >> 16);
}
__device__ __forceinline__ float bf2f(unsigned short h) {
    unsigned u = ((unsigned)h) << 16;
    return __builtin_bit_cast(float, u);
}

// xlds swizzle: logical (row m 0..15, col c 0..127) -> short index in a tile.
// 16B groups g = c>>3, XOR'd with (m>>2)<<1: epilogue reads (rg varies across
// lanes) and b128 writes both land 2 lanes/bank = conflict-free, zero padding.
__device__ __forceinline__ int xswz(int m, int c) {
    int g = (c >> 3) ^ ((m >> 2) << 1);
    return m * 128 + g * 8 + (c & 7);
}

__global__ __launch_bounds__(256, 2) void fused_qform(
        const float* __restrict__ x, const float* __restrict__ kern,
        const int* __restrict__ fd, unsigned short* __restrict__ wfrag,
        unsigned int* cnt, float* __restrict__ out) {
    __shared__ __align__(16) unsigned short wlds[16384];      // 32 KB, W B-frags
    __shared__ __align__(16) unsigned short xlds[8][2048];    // 32 KB, bf16-hi x

    const int tid = threadIdx.x;
    const int bid = blockIdx.x;

    // ---- phase 1: this block's 32 W' entries (8 lanes per length-64 dot) ----
    {
        int d = bid * 32 + (tid >> 3);   // entry: i = d>>7 (K idx), j = d&127 (N idx)
        int i = d >> 7, j = d & 127;
        int part = tid & 7;
        int fi = fd[i], fj = fd[j];
        const float4* ap = (const float4*)(kern + (i * FDIM + fj) * ODIM + part * 8);
        const float4* bp = (const float4*)(kern + (j * FDIM + fi) * ODIM + part * 8);
        float4 a0 = ap[0], a1 = ap[1];
        float4 b0 = bp[0], b1 = bp[1];
        float s = a0.x * b0.x + a0.y * b0.y + a0.z * b0.z + a0.w * b0.w +
                  a1.x * b1.x + a1.y * b1.y + a1.z * b1.z + a1.w * b1.w;
        s += __shfl_xor(s, 1, 64);
        s += __shfl_xor(s, 2, 64);
        s += __shfl_xor(s, 4, 64);
        if (part == 0) {
            float w = (i == j) ? 0.f : 0.5f * s;
            int kt = i >> 5, kc = (i >> 3) & 3, e = i & 7;
            wfrag[(((j >> 4) * 4 + kt) * 64 + kc * 16 + (j & 15)) * 8 + e] = f2bf_rne(w);
        }
    }
    __threadfence();   // release: push W stores device-visible
    __syncthreads();
    if (tid == 0)
        __hip_atomic_fetch_add(cnt, 1u, __ATOMIC_RELEASE, __HIP_MEMORY_SCOPE_AGENT);

    // ---- phase 2a: two 16-row x tiles per wave -> fragments + staged bf16-hi ----
    const int wave = tid >> 6, lane = tid & 63;
    const int row = lane & 15, kc = lane >> 4;
    const int t0 = wave * 2, t1 = t0 + 1;        // local tiles 0..7
    const size_t base = (size_t)bid * 128;       // block's first batch row
    const float* xp0 = x + (base + (size_t)(t0 * 16 + row)) * NN;
    const float* xp1 = x + (base + (size_t)(t1 * 16 + row)) * NN;

    s16x8 ah0[4], al0[4], ah1[4], al1[4];
#pragma unroll
    for (int kt = 0; kt < 4; ++kt) {
        const float4* p0 = (const float4*)(xp0 + kt * 32 + kc * 8);
        const float4* p1 = (const float4*)(xp1 + kt * 32 + kc * 8);
        float4 v00 = p0[0], v01 = p0[1], v10 = p1[0], v11 = p1[1];
        float vs0[8] = {v00.x, v00.y, v00.z, v00.w, v01.x, v01.y, v01.z, v01.w};
        float vs1[8] = {v10.x, v10.y, v10.z, v10.w, v11.x, v11.y, v11.z, v11.w};
        s16x8 hv0, hv1;
#pragma unroll
        for (int e = 0; e < 8; ++e) {
            unsigned short h0 = f2bf_rne(vs0[e]);
            unsigned short h1 = f2bf_rne(vs1[e]);
            hv0[e] = (short)h0; hv1[e] = (short)h1;
            ah0[kt][e] = (short)h0; ah1[kt][e] = (short)h1;
            float l0f = vs0[e] - bf2f(h0);
            float l1f = vs1[e] - bf2f(h1);
            al0[kt][e] = (short)(unsigned short)(__builtin_bit_cast(unsigned, l0f) >> 16);
            al1[kt][e] = (short)(unsigned short)(__builtin_bit_cast(unsigned, l1f) >> 16);
        }
        *(s16x8*)&xlds[t0][xswz(row, kt * 32 + kc * 8)] = hv0;
        *(s16x8*)&xlds[t1][xswz(row, kt * 32 + kc * 8)] = hv1;
    }

    // ---- device barrier: all 512 blocks' W entries written ----
    if (tid == 0) {
        long iters = 0;
        while (__hip_atomic_load(cnt, __ATOMIC_RELAXED, __HIP_MEMORY_SCOPE_AGENT) < NBLK &&
               iters < 10000000L) {   // bounded: ~1 s worst case, never hangs
            __builtin_amdgcn_s_sleep(2);
            ++iters;
        }
    }
    __syncthreads();
    __threadfence();   // acquire: invalidate L1/L2 before reading wfrag

    // ---- stage W' B-frags to LDS (async direct-to-LDS, linear layout) ----
    {
        const char* gsrc = (const char*)wfrag;
        char* ldst = (char*)wlds;
#pragma unroll
        for (int t = 0; t < 8; ++t) {
            int off = t * 4096 + tid * 16;
            __builtin_amdgcn_global_load_lds((gbl_void_t*)(gsrc + off),
                                             (lds_void_t*)(ldst + off), 16, 0, 0);
        }
    }
    __syncthreads();   // drains vmcnt (W) + lgkm (xlds writes)

    // ---- MFMA: Y = Xh*W + Xl*W, both tiles share each B-frag read ----
    f32x4 acc0[8], acc1[8];
#pragma unroll
    for (int nt = 0; nt < 8; ++nt) {
        f32x4 c0 = {0.f, 0.f, 0.f, 0.f}, c1 = {0.f, 0.f, 0.f, 0.f};
#pragma unroll
        for (int kt = 0; kt < 4; ++kt) {
            s16x8 bf = *(const s16x8*)&wlds[((nt * 4 + kt) * 64 + lane) * 8];
            c0 = __builtin_amdgcn_mfma_f32_16x16x32_bf16(ah0[kt], bf, c0, 0, 0, 0);
            c0 = __builtin_amdgcn_mfma_f32_16x16x32_bf16(al0[kt], bf, c0, 0, 0, 0);
            c1 = __builtin_amdgcn_mfma_f32_16x16x32_bf16(ah1[kt], bf, c1, 0, 0, 0);
            c1 = __builtin_amdgcn_mfma_f32_16x16x32_bf16(al1[kt], bf, c1, 0, 0, 0);
        }
        acc0[nt] = c0; acc1[nt] = c1;
    }

    // ---- epilogue: out[m] = sum_n Y[m][n]*xh[m][n]; D: col=lane&15, row=rg*4+r ----
    const int rg = lane >> 4, cl = lane & 15;
    float q00 = 0, q01 = 0, q02 = 0, q03 = 0;
    float q10 = 0, q11 = 0, q12 = 0, q13 = 0;
#pragma unroll
    for (int nt = 0; nt < 8; ++nt) {
        int c = nt * 16 + cl;
        q00 += acc0[nt][0] * bf2f(xlds[t0][xswz(rg * 4 + 0, c)]);
        q01 += acc0[nt][1] * bf2f(xlds[t0][xswz(rg * 4 + 1, c)]);
        q02 += acc0[nt][2] * bf2f(xlds[t0][xswz(rg * 4 + 2, c)]);
        q03 += acc0[nt][3] * bf2f(xlds[t0][xswz(rg * 4 + 3, c)]);
        q10 += acc1[nt][0] * bf2f(xlds[t1][xswz(rg * 4 + 0, c)]);
        q11 += acc1[nt][1] * bf2f(xlds[t1][xswz(rg * 4 + 1, c)]);
        q12 += acc1[nt][2] * bf2f(xlds[t1][xswz(rg * 4 + 2, c)]);
        q13 += acc1[nt][3] * bf2f(xlds[t1][xswz(rg * 4 + 3, c)]);
    }
#pragma unroll
    for (int m = 1; m <= 8; m <<= 1) {
        q00 += __shfl_xor(q00, m, 64); q01 += __shfl_xor(q01, m, 64);
        q02 += __shfl_xor(q02, m, 64); q03 += __shfl_xor(q03, m, 64);
        q10 += __shfl_xor(q10, m, 64); q11 += __shfl_xor(q11, m, 64);
        q12 += __shfl_xor(q12, m, 64); q13 += __shfl_xor(q13, m, 64);
    }
    if (cl == 0) {
        float* o0 = out + base + t0 * 16 + rg * 4;
        float* o1 = out + base + t1 * 16 + rg * 4;
        o0[0] = q00; o0[1] = q01; o0[2] = q02; o0[3] = q03;
        o1[0] = q10; o1[1] = q11; o1[2] = q12; o1[3] = q13;
    }
}

extern "C" void kernel_launch(void* const* d_in, const int* in_sizes, int n_in,
                              void* d_out, int out_size, void* d_ws, size_t ws_size,
                              hipStream_t stream) {
    const float* x = (const float*)d_in[0];
    const float* kern = (const float*)d_in[1];
    const int* fd = (const int*)d_in[2];
    float* out = (float*)d_out;
    unsigned short* wfrag = (unsigned short*)d_ws;                  // 32 KB
    unsigned int* cnt = (unsigned int*)((char*)d_ws + 32768);       // 4 B counter

    hipMemsetAsync(cnt, 0, 4, stream);  // async fill: graph-capture safe
    fused_qform<<<dim3(NBLK), dim3(256), 0, stream>>>(x, kern, fd, wfrag, cnt, out);
}

// Round 4
// 18.715 us; speedup vs baseline: 5.1252x; 5.1252x over previous
//
#include <hip/hip_runtime.h>

#define NB 65536
#define NN 128
#define FDIM 16
#define ODIM 64

typedef __attribute__((ext_vector_type(8))) short s16x8;
typedef __attribute__((ext_vector_type(4))) float f32x4;
typedef __attribute__((address_space(3))) void lds_void_t;
typedef const __attribute__((address_space(1))) void gbl_void_t;

__device__ __forceinline__ unsigned short f2bf_rne(float f) {
    unsigned u = __builtin_bit_cast(unsigned, f);
    u += 0x7FFFu + ((u >> 16) & 1u);
    return (unsigned short)(u >> 16);
}
__device__ __forceinline__ float bf2f(unsigned short h) {
    unsigned u = ((unsigned)h) << 16;
    return __builtin_bit_cast(float, u);
}

// xlds swizzle: (row m, col c) -> short index. 16B groups XOR'd by (m>>2)<<1:
// b128 writes and epilogue u16 reads both conflict-free (validated round 3).
__device__ __forceinline__ int xswz(int m, int c) {
    int g = (c >> 3) ^ ((m >> 2) << 1);
    return m * 128 + g * 8 + (c & 7);
}

// ---------------------------------------------------------------------------
// Kernel 1 (H2 test): W' = 0.5*S, bf16 B-fragment layout. 512 blocks x 256
// threads, 8 lanes per length-64 dot -> full-GPU, ~1 us (round-1/2 version
// was 128 blocks x 2 waves: half the GPU idle, suspected multi-us).
// ---------------------------------------------------------------------------
__global__ __launch_bounds__(256) void prep_w_fast(const float* __restrict__ kern,
                                                   const int* __restrict__ fd,
                                                   unsigned short* __restrict__ wfrag) {
    int d = blockIdx.x * 32 + (threadIdx.x >> 3);  // entry: i=K idx, j=N idx
    int i = d >> 7, j = d & 127;
    int part = threadIdx.x & 7;
    int fi = fd[i], fj = fd[j];
    const float4* ap = (const float4*)(kern + (i * FDIM + fj) * ODIM + part * 8);
    const float4* bp = (const float4*)(kern + (j * FDIM + fi) * ODIM + part * 8);
    float4 a0 = ap[0], a1 = ap[1];
    float4 b0 = bp[0], b1 = bp[1];
    float s = a0.x * b0.x + a0.y * b0.y + a0.z * b0.z + a0.w * b0.w +
              a1.x * b1.x + a1.y * b1.y + a1.z * b1.z + a1.w * b1.w;
    s += __shfl_xor(s, 1, 64);
    s += __shfl_xor(s, 2, 64);
    s += __shfl_xor(s, 4, 64);
    if (part == 0) {
        float w = (i == j) ? 0.f : 0.5f * s;
        int kt = i >> 5, kc = (i >> 3) & 3, e = i & 7;
        wfrag[(((j >> 4) * 4 + kt) * 64 + kc * 16 + (j & 15)) * 8 + e] = f2bf_rne(w);
    }
}

// ---------------------------------------------------------------------------
// Kernel 2: out[b] = x_b^T W' x_b. 512 blocks x 256 threads (4 waves),
// 2 tiles/wave sharing each W B-frag ds_read (halves W LDS traffic vs r2),
// xswz'd xlds (conflict-free epilogue). LDS = 64 KB -> 2 blocks/CU.
// ---------------------------------------------------------------------------
__global__ __launch_bounds__(256, 2) void qform(const float* __restrict__ x,
                                                const unsigned short* __restrict__ wfrag,
                                                float* __restrict__ out) {
    __shared__ __align__(16) unsigned short wlds[16384];     // 32 KB
    __shared__ __align__(16) unsigned short xlds[8][2048];   // 32 KB

    const int tid = threadIdx.x;
    const int bid = blockIdx.x;

    // async W stage: 32 KB, linear layout, direct-to-LDS
    {
        const char* gsrc = (const char*)wfrag;
        char* ldst = (char*)wlds;
#pragma unroll
        for (int t = 0; t < 8; ++t) {
            int off = t * 4096 + tid * 16;
            __builtin_amdgcn_global_load_lds((gbl_void_t*)(gsrc + off),
                                             (lds_void_t*)(ldst + off), 16, 0, 0);
        }
    }

    const int wave = tid >> 6, lane = tid & 63;
    const int row = lane & 15, kc = lane >> 4;
    const int t0 = wave * 2, t1 = t0 + 1;
    const size_t base = (size_t)bid * 128;
    const float* xp0 = x + (base + (size_t)(t0 * 16 + row)) * NN;
    const float* xp1 = x + (base + (size_t)(t1 * 16 + row)) * NN;

    s16x8 ah0[4], al0[4], ah1[4], al1[4];
#pragma unroll
    for (int kt = 0; kt < 4; ++kt) {
        const float4* p0 = (const float4*)(xp0 + kt * 32 + kc * 8);
        const float4* p1 = (const float4*)(xp1 + kt * 32 + kc * 8);
        float4 v00 = p0[0], v01 = p0[1], v10 = p1[0], v11 = p1[1];
        float vs0[8] = {v00.x, v00.y, v00.z, v00.w, v01.x, v01.y, v01.z, v01.w};
        float vs1[8] = {v10.x, v10.y, v10.z, v10.w, v11.x, v11.y, v11.z, v11.w};
        s16x8 hv0, hv1;
#pragma unroll
        for (int e = 0; e < 8; ++e) {
            unsigned short h0 = f2bf_rne(vs0[e]);
            unsigned short h1 = f2bf_rne(vs1[e]);
            hv0[e] = (short)h0; hv1[e] = (short)h1;
            ah0[kt][e] = (short)h0; ah1[kt][e] = (short)h1;
            float l0f = vs0[e] - bf2f(h0);
            float l1f = vs1[e] - bf2f(h1);
            al0[kt][e] = (short)(unsigned short)(__builtin_bit_cast(unsigned, l0f) >> 16);
            al1[kt][e] = (short)(unsigned short)(__builtin_bit_cast(unsigned, l1f) >> 16);
        }
        *(s16x8*)&xlds[t0][xswz(row, kt * 32 + kc * 8)] = hv0;
        *(s16x8*)&xlds[t1][xswz(row, kt * 32 + kc * 8)] = hv1;
    }
    __syncthreads();  // drains vmcnt (W stage) + lgkm (xlds writes)

    f32x4 acc0[8], acc1[8];
#pragma unroll
    for (int nt = 0; nt < 8; ++nt) {
        f32x4 c0 = {0.f, 0.f, 0.f, 0.f}, c1 = {0.f, 0.f, 0.f, 0.f};
#pragma unroll
        for (int kt = 0; kt < 4; ++kt) {
            s16x8 bf = *(const s16x8*)&wlds[((nt * 4 + kt) * 64 + lane) * 8];
            c0 = __builtin_amdgcn_mfma_f32_16x16x32_bf16(ah0[kt], bf, c0, 0, 0, 0);
            c0 = __builtin_amdgcn_mfma_f32_16x16x32_bf16(al0[kt], bf, c0, 0, 0, 0);
            c1 = __builtin_amdgcn_mfma_f32_16x16x32_bf16(ah1[kt], bf, c1, 0, 0, 0);
            c1 = __builtin_amdgcn_mfma_f32_16x16x32_bf16(al1[kt], bf, c1, 0, 0, 0);
        }
        acc0[nt] = c0; acc1[nt] = c1;
    }

    // epilogue: D layout col=lane&15, row=(lane>>4)*4+reg (m89-verified)
    const int rg = lane >> 4, cl = lane & 15;
    float q00 = 0, q01 = 0, q02 = 0, q03 = 0;
    float q10 = 0, q11 = 0, q12 = 0, q13 = 0;
#pragma unroll
    for (int nt = 0; nt < 8; ++nt) {
        int c = nt * 16 + cl;
        q00 += acc0[nt][0] * bf2f(xlds[t0][xswz(rg * 4 + 0, c)]);
        q01 += acc0[nt][1] * bf2f(xlds[t0][xswz(rg * 4 + 1, c)]);
        q02 += acc0[nt][2] * bf2f(xlds[t0][xswz(rg * 4 + 2, c)]);
        q03 += acc0[nt][3] * bf2f(xlds[t0][xswz(rg * 4 + 3, c)]);
        q10 += acc1[nt][0] * bf2f(xlds[t1][xswz(rg * 4 + 0, c)]);
        q11 += acc1[nt][1] * bf2f(xlds[t1][xswz(rg * 4 + 1, c)]);
        q12 += acc1[nt][2] * bf2f(xlds[t1][xswz(rg * 4 + 2, c)]);
        q13 += acc1[nt][3] * bf2f(xlds[t1][xswz(rg * 4 + 3, c)]);
    }
#pragma unroll
    for (int m = 1; m <= 8; m <<= 1) {
        q00 += __shfl_xor(q00, m, 64); q01 += __shfl_xor(q01, m, 64);
        q02 += __shfl_xor(q02, m, 64); q03 += __shfl_xor(q03, m, 64);
        q10 += __shfl_xor(q10, m, 64); q11 += __shfl_xor(q11, m, 64);
        q12 += __shfl_xor(q12, m, 64); q13 += __shfl_xor(q13, m, 64);
    }
    if (cl == 0) {
        float* o0 = out + base + t0 * 16 + rg * 4;
        float* o1 = out + base + t1 * 16 + rg * 4;
        o0[0] = q00; o0[1] = q01; o0[2] = q02; o0[3] = q03;
        o1[0] = q10; o1[1] = q11; o1[2] = q12; o1[3] = q13;
    }
}

extern "C" void kernel_launch(void* const* d_in, const int* in_sizes, int n_in,
                              void* d_out, int out_size, void* d_ws, size_t ws_size,
                              hipStream_t stream) {
    const float* x = (const float*)d_in[0];
    const float* kern = (const float*)d_in[1];
    const int* fd = (const int*)d_in[2];
    float* out = (float*)d_out;
    unsigned short* wfrag = (unsigned short*)d_ws;  // 32 KB used

    prep_w_fast<<<dim3(512), dim3(256), 0, stream>>>(kern, fd, wfrag);
    qform<<<dim3(512), dim3(256), 0, stream>>>(x, wfrag, out);
}

// Round 5
// 17.915 us; speedup vs baseline: 5.3541x; 1.0447x over previous
//
#include <hip/hip_runtime.h>

#define NB 65536
#define NN 128
#define FDIM 16
#define ODIM 64

typedef __attribute__((ext_vector_type(8))) short s16x8;
typedef __attribute__((ext_vector_type(4))) float f32x4;
typedef __attribute__((address_space(3))) void lds_void_t;
typedef const __attribute__((address_space(1))) void gbl_void_t;

__device__ __forceinline__ unsigned short f2bf_rne(float f) {
    unsigned u = __builtin_bit_cast(unsigned, f);
    u += 0x7FFFu + ((u >> 16) & 1u);
    return (unsigned short)(u >> 16);
}

// ---------------------------------------------------------------------------
// Kernel 1: W' = 0.5*S (symmetric, zero diag), bf16 B-fragment layout.
// 512 blocks x 256 threads, 8 lanes per length-64 dot. (validated r3/r4)
// ---------------------------------------------------------------------------
__global__ __launch_bounds__(256) void prep_w_fast(const float* __restrict__ kern,
                                                   const int* __restrict__ fd,
                                                   unsigned short* __restrict__ wfrag) {
    int d = blockIdx.x * 32 + (threadIdx.x >> 3);  // entry: i=K idx, j=N idx
    int i = d >> 7, j = d & 127;
    int part = threadIdx.x & 7;
    int fi = fd[i], fj = fd[j];
    const float4* ap = (const float4*)(kern + (i * FDIM + fj) * ODIM + part * 8);
    const float4* bp = (const float4*)(kern + (j * FDIM + fi) * ODIM + part * 8);
    float4 a0 = ap[0], a1 = ap[1];
    float4 b0 = bp[0], b1 = bp[1];
    float s = a0.x * b0.x + a0.y * b0.y + a0.z * b0.z + a0.w * b0.w +
              a1.x * b1.x + a1.y * b1.y + a1.z * b1.z + a1.w * b1.w;
    s += __shfl_xor(s, 1, 64);
    s += __shfl_xor(s, 2, 64);
    s += __shfl_xor(s, 4, 64);
    if (part == 0) {
        float w = (i == j) ? 0.f : 0.5f * s;
        int kt = i >> 5, kc = (i >> 3) & 3, e = i & 7;
        wfrag[(((j >> 4) * 4 + kt) * 64 + kc * 16 + (j & 15)) * 8 + e] = f2bf_rne(w);
    }
}

// ---------------------------------------------------------------------------
// Kernel 2: out[b] = x_b^T W' x_b.  Latency/occupancy-focused rebuild:
//  - LDS = wlds only (32 KB) -> 4 blocks/CU, 16 waves/CU (was 2 blk, 8 waves)
//  - single bf16 MFMA pass (lo-pass dropped; error budget analysis in notes)
//  - epilogue reads x fp32 straight from global (L1/L2-hot), no xlds
//  - epilogue fused into nt loop: acc regs 64 -> 8
// 512 blocks x 256 thr (4 waves), 2 tiles/wave sharing each W B-frag read.
// ---------------------------------------------------------------------------
__global__ __launch_bounds__(256, 4) void qform(const float* __restrict__ x,
                                                const unsigned short* __restrict__ wfrag,
                                                float* __restrict__ out) {
    __shared__ __align__(16) unsigned short wlds[16384];  // 32 KB

    const int tid = threadIdx.x;
    const int bid = blockIdx.x;

    // async W stage: 32 KB, linear layout, direct-to-LDS (no VGPR round-trip)
    {
        const char* gsrc = (const char*)wfrag;
        char* ldst = (char*)wlds;
#pragma unroll
        for (int t = 0; t < 8; ++t) {
            int off = t * 4096 + tid * 16;
            __builtin_amdgcn_global_load_lds((gbl_void_t*)(gsrc + off),
                                             (lds_void_t*)(ldst + off), 16, 0, 0);
        }
    }

    const int wave = tid >> 6, lane = tid & 63;
    const int row = lane & 15, kc = lane >> 4;
    const int t0 = wave * 2, t1 = t0 + 1;
    const size_t base = (size_t)bid * 128;
    const float* xp0 = x + (base + (size_t)(t0 * 16 + row)) * NN + kc * 8;
    const float* xp1 = x + (base + (size_t)(t1 * 16 + row)) * NN + kc * 8;

    // A-fragments: bf16(x), single pass
    s16x8 ah0[4], ah1[4];
#pragma unroll
    for (int kt = 0; kt < 4; ++kt) {
        const float4* p0 = (const float4*)(xp0 + kt * 32);
        const float4* p1 = (const float4*)(xp1 + kt * 32);
        float4 v00 = p0[0], v01 = p0[1], v10 = p1[0], v11 = p1[1];
        float vs0[8] = {v00.x, v00.y, v00.z, v00.w, v01.x, v01.y, v01.z, v01.w};
        float vs1[8] = {v10.x, v10.y, v10.z, v10.w, v11.x, v11.y, v11.z, v11.w};
#pragma unroll
        for (int e = 0; e < 8; ++e) {
            ah0[kt][e] = (short)f2bf_rne(vs0[e]);
            ah1[kt][e] = (short)f2bf_rne(vs1[e]);
        }
    }
    __syncthreads();  // drains vmcnt (W stage) — A-frag loads drained too

    // epilogue base pointers: thread (rg,cl) needs x[tile*16+rg*4+r][nt*16+cl]
    const int rg = lane >> 4, cl = lane & 15;
    const float* e0 = x + (base + (size_t)(t0 * 16 + rg * 4)) * NN + cl;
    const float* e1 = x + (base + (size_t)(t1 * 16 + rg * 4)) * NN + cl;

    float q00 = 0, q01 = 0, q02 = 0, q03 = 0;
    float q10 = 0, q11 = 0, q12 = 0, q13 = 0;
#pragma unroll
    for (int nt = 0; nt < 8; ++nt) {
        f32x4 c0 = {0.f, 0.f, 0.f, 0.f}, c1 = {0.f, 0.f, 0.f, 0.f};
#pragma unroll
        for (int kt = 0; kt < 4; ++kt) {
            s16x8 bf = *(const s16x8*)&wlds[((nt * 4 + kt) * 64 + lane) * 8];
            c0 = __builtin_amdgcn_mfma_f32_16x16x32_bf16(ah0[kt], bf, c0, 0, 0, 0);
            c1 = __builtin_amdgcn_mfma_f32_16x16x32_bf16(ah1[kt], bf, c1, 0, 0, 0);
        }
        // D layout (m89-verified): col = lane&15, row = (lane>>4)*4 + reg
        const int nc = nt * 16;
        q00 += c0[0] * e0[0 * NN + nc];
        q01 += c0[1] * e0[1 * NN + nc];
        q02 += c0[2] * e0[2 * NN + nc];
        q03 += c0[3] * e0[3 * NN + nc];
        q10 += c1[0] * e1[0 * NN + nc];
        q11 += c1[1] * e1[1 * NN + nc];
        q12 += c1[2] * e1[2 * NN + nc];
        q13 += c1[3] * e1[3 * NN + nc];
    }
#pragma unroll
    for (int m = 1; m <= 8; m <<= 1) {
        q00 += __shfl_xor(q00, m, 64); q01 += __shfl_xor(q01, m, 64);
        q02 += __shfl_xor(q02, m, 64); q03 += __shfl_xor(q03, m, 64);
        q10 += __shfl_xor(q10, m, 64); q11 += __shfl_xor(q11, m, 64);
        q12 += __shfl_xor(q12, m, 64); q13 += __shfl_xor(q13, m, 64);
    }
    if (cl == 0) {
        float4 o0 = {q00, q01, q02, q03};
        float4 o1 = {q10, q11, q12, q13};
        *(float4*)(out + base + t0 * 16 + rg * 4) = o0;
        *(float4*)(out + base + t1 * 16 + rg * 4) = o1;
    }
}

extern "C" void kernel_launch(void* const* d_in, const int* in_sizes, int n_in,
                              void* d_out, int out_size, void* d_ws, size_t ws_size,
                              hipStream_t stream) {
    const float* x = (const float*)d_in[0];
    const float* kern = (const float*)d_in[1];
    const int* fd = (const int*)d_in[2];
    float* out = (float*)d_out;
    unsigned short* wfrag = (unsigned short*)d_ws;  // 32 KB used

    prep_w_fast<<<dim3(512), dim3(256), 0, stream>>>(kern, fd, wfrag);
    qform<<<dim3(512), dim3(256), 0, stream>>>(x, wfrag, out);
}